// Round 4
// baseline (165.637 us; speedup 1.0000x reference)
//
#include <hip/hip_runtime.h>
#include <hip/hip_bf16.h>
#include <hip/hip_cooperative_groups.h>

namespace cg = cooperative_groups;

// NT-Xent with more negatives: N=2048, D=128, k=4 augs.
// sim = norm(z[4096,128]) @ norm(z_all[8192,128])^T * 2   (T=0.5)
// loss = mean_rows( logsumexp(masked sim) - pos )
// R11: LDS-free MFMA GEMM, fragments direct from L2-resident Bn (2 MB).
// R12: tile rebalance (256x512) -> NULL (not L2-BW bound).
// R13: pre-scaled Bn (epilogue = exp2+add), B prefetch reorder, setprio
//   -> NULL (not inner-loop cycle bound).
// R14: two nulls => limiter is structure: 3 serial launches + dispatch
//   tails + 4-wave serial finisher, all in the DVFS-depressed window after
//   the harness's 42us fill. Fuse into ONE cooperative launch (256 blocks
//   x 1024 thr = 1 block/CU, co-resident) with two grid.sync()s:
//   phase1 normalize (32 rows/block), phase2 GEMM (R13 body), phase3
//   finisher (16 waves/block, 1 row/wave). If this nulls too, the wall is
//   the fill+ramp itself -> roofline.

#define NN      2048
#define DD      128
#define TWO_N   4096
#define FOUR_N  8192
#define CTG     16     // col groups (8192 / 512)
#define SQRT_C  1.6986436f            // sqrt(2*log2(e)); scaled dot = 2*log2e*sim
#define LN2     0.6931471805599453f

using frag_ab = __attribute__((ext_vector_type(8))) short;  // 8 bf16 = 16 B
using f32x4   = __attribute__((ext_vector_type(4))) float;

__global__ __launch_bounds__(1024, 4) void kfused(
    const float* __restrict__ p0, const float* __restrict__ p1,
    const float* __restrict__ p2, const float* __restrict__ p3,
    short* __restrict__ Bn, float* __restrict__ pS, float* __restrict__ out) {
  cg::grid_group grid = cg::this_grid();
  __shared__ float sS[256][5];   // phase2 merge scratch; phase3 reuses [w][0]

  int t = threadIdx.x, wave = t >> 6, lane = t & 63;
  int quad = lane >> 4, l16 = lane & 15;

  // ---------- Phase 1: L2-normalize -> bf16 * SQRT_C (32 rows/block) -----
  if (blockIdx.x == 0 && t == 0) out[0] = 0.0f;
  {
    int l32 = lane & 31;
    int row = blockIdx.x * 32 + wave * 2 + (lane >> 5);   // 0..8191
    int q = row >> 11, idx = row & (NN - 1);
    const float* src = (q == 0) ? p0 : (q == 1) ? p1 : (q == 2) ? p2 : p3;
    float4 v = ((const float4*)(src + (size_t)idx * DD))[l32];
    float ss = v.x * v.x + v.y * v.y + v.z * v.z + v.w * v.w;
    #pragma unroll
    for (int sh = 1; sh < 32; sh <<= 1) ss += __shfl_xor(ss, sh, 64);
    float inv = SQRT_C / fmaxf(sqrtf(ss), 1e-8f);
    __hip_bfloat162 h0, h1;
    h0.x = __float2bfloat16(v.x * inv); h0.y = __float2bfloat16(v.y * inv);
    h1.x = __float2bfloat16(v.z * inv); h1.y = __float2bfloat16(v.w * inv);
    uint2 u;
    u.x = *(unsigned int*)&h0;
    u.y = *(unsigned int*)&h1;
    *(uint2*)(Bn + (size_t)row * DD + l32 * 4) = u;
  }
  grid.sync();

  // ---------- Phase 2: LDS-free GEMM + partial sumexp --------------------
  // Block: 256 A-rows x 512 B-cols (8 streamed 64-col tiles). Wave
  // (rowH=w>>2, colO=w&3): rows rowH*64..+64, cols colO*16..+16 per tile.
  // pS[row][by] = sum_{cols in 512-group} exp2(C*sim)  (= exp(2*sim)).
  {
    int rowH = wave >> 2, colO = wave & 3;
    int lin = blockIdx.x;                      // XCD-bijective swizzle
    int by = (lin & 7) | ((lin >> 7) << 3);    // 0..15
    int bx = (lin >> 3) & 15;                  // 0..15

    const short* gA = Bn + (size_t)(bx * 256 + rowH * 64 + l16) * DD + quad * 8;
    frag_ab a[4][4];                                  // [k][rf], 64 VGPR
    #pragma unroll
    for (int rf = 0; rf < 4; ++rf)
      #pragma unroll
      for (int k = 0; k < 4; ++k)
        a[k][rf] = *(const frag_ab*)(gA + (size_t)rf * 16 * DD + k * 32);

    const short* gB = Bn + (size_t)(by * 512 + colO * 16 + l16) * DD + quad * 8;

    float sAcc[4][4];
    #pragma unroll
    for (int rf = 0; rf < 4; ++rf)
      #pragma unroll
      for (int r = 0; r < 4; ++r) sAcc[rf][r] = 0.f;

    frag_ab bb[4];
    #pragma unroll
    for (int k = 0; k < 4; ++k)
      bb[k] = *(const frag_ab*)(gB + k * 32);

    #pragma unroll 1
    for (int g = 0; g < 8; ++g) {
      f32x4 acc[4];
      #pragma unroll
      for (int rf = 0; rf < 4; ++rf) acc[rf] = (f32x4){0.f, 0.f, 0.f, 0.f};

      __builtin_amdgcn_s_setprio(1);
      #pragma unroll
      for (int k = 0; k < 4; ++k)
        #pragma unroll
        for (int rf = 0; rf < 4; ++rf)
          acc[rf] = __builtin_amdgcn_mfma_f32_16x16x32_bf16(a[k][rf], bb[k], acc[rf], 0, 0, 0);
      __builtin_amdgcn_s_setprio(0);

      if (g < 7) {   // WAR-safe single-buffer prefetch of tile g+1
        const short* gBn = gB + (size_t)(g + 1) * 64 * DD;
        #pragma unroll
        for (int k = 0; k < 4; ++k)
          bb[k] = *(const frag_ab*)(gBn + k * 32);
      }
      __builtin_amdgcn_sched_barrier(0);  // pin loads before the epilogue

      #pragma unroll
      for (int rf = 0; rf < 4; ++rf)
        #pragma unroll
        for (int r = 0; r < 4; ++r)
          sAcc[rf][r] += __builtin_amdgcn_exp2f(acc[rf][r]);
    }

    #pragma unroll
    for (int rf = 0; rf < 4; ++rf)
      #pragma unroll
      for (int r = 0; r < 4; ++r) {
        float s = sAcc[rf][r];
        s += __shfl_xor(s, 1, 64);
        s += __shfl_xor(s, 2, 64);
        s += __shfl_xor(s, 4, 64);
        s += __shfl_xor(s, 8, 64);
        if (l16 == 0) sS[rowH * 64 + rf * 16 + quad * 4 + r][colO] = s;
      }
    __syncthreads();
    if (t < 256)
      pS[(size_t)(bx * 256 + t) * CTG + by] =
          (sS[t][0] + sS[t][1]) + (sS[t][2] + sS[t][3]);
  }
  grid.sync();

  // ---------- Phase 3: finisher (16 waves/block, 1 row/wave) -------------
  // Merge 16 group-partials, subtract 3 masked diagonal exps (self, aug3,
  // aug4), add pos term; block-reduce; one atomicAdd. Pre-scaled domain:
  // loss = ln2 * (log2(Sc) - dab_scaled).
  {
    int gr = blockIdx.x * 16 + wave;                  // 0..4095
    int idx = gr & (NN - 1), half = gr >> 11;
    float S = (lane < CTG) ? pS[(size_t)gr * CTG + lane] : 0.f;
    #pragma unroll
    for (int sh = 1; sh < 16; sh <<= 1) S += __shfl_xor(S, sh, 64);
    unsigned int ua = ((const unsigned int*)(Bn + (size_t)gr * DD))[lane];
    unsigned int ub = ((const unsigned int*)(Bn + (size_t)((1 - half) * NN + idx) * DD))[lane];
    unsigned int uc = ((const unsigned int*)(Bn + (size_t)(2 * NN + idx) * DD))[lane];
    unsigned int ud = ((const unsigned int*)(Bn + (size_t)(3 * NN + idx) * DD))[lane];
    float a0 = __uint_as_float((ua & 0xffffu) << 16), a1 = __uint_as_float(ua & 0xffff0000u);
    float b0 = __uint_as_float((ub & 0xffffu) << 16), b1 = __uint_as_float(ub & 0xffff0000u);
    float c0 = __uint_as_float((uc & 0xffffu) << 16), c1 = __uint_as_float(uc & 0xffff0000u);
    float d0 = __uint_as_float((ud & 0xffffu) << 16), d1 = __uint_as_float(ud & 0xffff0000u);
    float daa = a0 * a0 + a1 * a1;       // = C * (self dot)
    float dab = a0 * b0 + a1 * b1;       // = C * (pos dot)
    float dac = a0 * c0 + a1 * c1;
    float dad = a0 * d0 + a1 * d1;
    #pragma unroll
    for (int sh = 1; sh < 64; sh <<= 1) {
      daa += __shfl_xor(daa, sh, 64);
      dab += __shfl_xor(dab, sh, 64);
      dac += __shfl_xor(dac, sh, 64);
      dad += __shfl_xor(dad, sh, 64);
    }
    float Sc = S - __builtin_amdgcn_exp2f(daa)
                 - __builtin_amdgcn_exp2f(dac)
                 - __builtin_amdgcn_exp2f(dad);
    float loss = LN2 * (__log2f(Sc) - dab);
    if (lane == 0) sS[wave][0] = loss;
    __syncthreads();
    if (t == 0) {
      float acc = 0.f;
      #pragma unroll
      for (int w = 0; w < 16; ++w) acc += sS[w][0];
      atomicAdd(out, acc * (1.0f / (float)TWO_N));
    }
  }
}

extern "C" void kernel_launch(void* const* d_in, const int* in_sizes, int n_in,
                              void* d_out, int out_size, void* d_ws, size_t ws_size,
                              hipStream_t stream) {
  (void)in_sizes; (void)n_in; (void)out_size; (void)ws_size;
  const float* p0 = (const float*)d_in[0];
  const float* p1 = (const float*)d_in[1];
  const float* p2 = (const float*)d_in[2];
  const float* p3 = (const float*)d_in[3];

  // ws layout: Bn bf16 [8192][128] (2 MB) | pS f32 [4096][16] (256 KB)
  short* Bn = (short*)d_ws;
  float* pS = (float*)((char*)d_ws + (size_t)FOUR_N * DD * sizeof(short));
  float* out = (float*)d_out;

  void* args[] = {(void*)&p0, (void*)&p1, (void*)&p2, (void*)&p3,
                  (void*)&Bn, (void*)&pS, (void*)&out};
  hipLaunchCooperativeKernel((void*)kfused, dim3(256), dim3(1024), args, 0, stream);
}

// Round 5
// 130.014 us; speedup vs baseline: 1.2740x; 1.2740x over previous
//
#include <hip/hip_runtime.h>
#include <hip/hip_bf16.h>

// NT-Xent with more negatives: N=2048, D=128, k=4 augs.
// sim = norm(z[4096,128]) @ norm(z_all[8192,128])^T * 2   (T=0.5)
// loss = mean_rows( logsumexp(masked sim) - pos )
// R11: LDS-free MFMA GEMM, fragments direct from L2-resident Bn (2 MB).
// R12: tile rebalance (256x512) -> NULL (not L2-BW bound).
// R13: pre-scaled Bn (epilogue = exp2+add), prefetch reorder -> NULL.
// R14: cooperative single-kernel fusion -> 165us REGRESSION. Confounded:
//   kfused compiled to 64 VGPR (main loop spilled; needs ~112) and
//   grid.sync does cross-XCD L2 wb/inv + spin. Reverted.
// R15: test structure cost WITHOUT grid.sync: fuse kfin into kgemm via
//   last-arriver pattern (threadfence + atomicAdd(cnt[bx]); 16th block
//   finishes its 256 rows). No spinning -> no residency assumption.
//   knorm widened to 256 blocks x 1024 thr; zeroes cnt+out. 2 launches.
//   Pre-commit: if delta < 3us => wall = fill+DVFS ramp => ROOFLINE.

#define NN      2048
#define DD      128
#define TWO_N   4096
#define FOUR_N  8192
#define CTG     16     // col groups (8192 / 512)
#define SQRT_C  1.6986436f            // sqrt(2*log2(e)); scaled dot = 2*log2e*sim
#define LN2     0.6931471805599453f

using frag_ab = __attribute__((ext_vector_type(8))) short;  // 8 bf16 = 16 B
using f32x4   = __attribute__((ext_vector_type(4))) float;

// ---------------- Kernel 1: L2-normalize rows -> bf16 * SQRT_C -----------
// 256 blocks x 1024 thr, 32 rows/block (half-wave per row, float4/lane).
// Also zeroes out[0] and cnt[0..15].
__global__ __launch_bounds__(1024) void knorm(const float* __restrict__ p0,
                                              const float* __restrict__ p1,
                                              const float* __restrict__ p2,
                                              const float* __restrict__ p3,
                                              short* __restrict__ Bn,
                                              float* __restrict__ out,
                                              unsigned int* __restrict__ cnt) {
  int t = threadIdx.x, wave = t >> 6, lane = t & 63;
  if (blockIdx.x == 0) {
    if (t == 0) out[0] = 0.0f;
    if (t < 16) cnt[t] = 0u;
  }
  int l32 = lane & 31;
  int row = blockIdx.x * 32 + wave * 2 + (lane >> 5);   // 0..8191
  int q = row >> 11, idx = row & (NN - 1);
  const float* src = (q == 0) ? p0 : (q == 1) ? p1 : (q == 2) ? p2 : p3;
  float4 v = ((const float4*)(src + (size_t)idx * DD))[l32];
  float ss = v.x * v.x + v.y * v.y + v.z * v.z + v.w * v.w;
  #pragma unroll
  for (int sh = 1; sh < 32; sh <<= 1) ss += __shfl_xor(ss, sh, 64);
  float inv = SQRT_C / fmaxf(sqrtf(ss), 1e-8f);
  __hip_bfloat162 h0, h1;
  h0.x = __float2bfloat16(v.x * inv); h0.y = __float2bfloat16(v.y * inv);
  h1.x = __float2bfloat16(v.z * inv); h1.y = __float2bfloat16(v.w * inv);
  uint2 u;
  u.x = *(unsigned int*)&h0;
  u.y = *(unsigned int*)&h1;
  *(uint2*)(Bn + (size_t)row * DD + l32 * 4) = u;
}

// ---------------- Kernel 2: LDS-free GEMM + sumexp + fused finisher ------
// 256 blocks x 1024 thr = 16 waves = 4/SIMD, 1 block/CU.
// Block (bx,by): 256 A-rows x 512 B-cols (8 streamed 64-col tiles).
// pS[row][by] = sum_{cols in 512-group} exp2(C*sim)  (= exp(2*sim)).
// Last arriver of each bx group (atomicAdd on cnt[bx]) finishes rows
// bx*256..+256: merge 16 partials, subtract 3 masked diagonal exps,
// add pos term, one atomicAdd into out.
__global__ __launch_bounds__(1024, 4) void kgemm(const short* __restrict__ Bn,
                                                 float* __restrict__ pS,
                                                 unsigned int* __restrict__ cnt,
                                                 float* __restrict__ out) {
  __shared__ float sS[256][5];   // merge scratch; finisher reuses [w][0]
  __shared__ int sLast;

  int t = threadIdx.x, wave = t >> 6, lane = t & 63;
  int quad = lane >> 4, l16 = lane & 15;
  int rowH = wave >> 2, colO = wave & 3;

  // XCD-bijective swizzle: xcd = lin & 7 (dispatch round-robin).
  int lin = blockIdx.x;                      // 0..255
  int by = (lin & 7) | ((lin >> 7) << 3);    // 0..15
  int bx = (lin >> 3) & 15;                  // 0..15

  // Hoist A fragments: rows bx*256 + rowH*64 + rf*16 + l16, chunk k*4+quad.
  const short* gA = Bn + (size_t)(bx * 256 + rowH * 64 + l16) * DD + quad * 8;
  frag_ab a[4][4];                                  // [k][rf], 64 VGPR
  #pragma unroll
  for (int rf = 0; rf < 4; ++rf)
    #pragma unroll
    for (int k = 0; k < 4; ++k)
      a[k][rf] = *(const frag_ab*)(gA + (size_t)rf * 16 * DD + k * 32);

  // B base: col (sim-space) = by*512 + g*64 + colO*16 + l16.
  const short* gB = Bn + (size_t)(by * 512 + colO * 16 + l16) * DD + quad * 8;

  float sAcc[4][4];
  #pragma unroll
  for (int rf = 0; rf < 4; ++rf)
    #pragma unroll
    for (int r = 0; r < 4; ++r) sAcc[rf][r] = 0.f;

  // Prime tile 0's B fragments (single buffer, overwritten each iter).
  frag_ab bb[4];
  #pragma unroll
  for (int k = 0; k < 4; ++k)
    bb[k] = *(const frag_ab*)(gB + k * 32);

  #pragma unroll 1
  for (int g = 0; g < 8; ++g) {
    f32x4 acc[4];
    #pragma unroll
    for (int rf = 0; rf < 4; ++rf) acc[rf] = (f32x4){0.f, 0.f, 0.f, 0.f};

    __builtin_amdgcn_s_setprio(1);
    #pragma unroll
    for (int k = 0; k < 4; ++k)
      #pragma unroll
      for (int rf = 0; rf < 4; ++rf)
        acc[rf] = __builtin_amdgcn_mfma_f32_16x16x32_bf16(a[k][rf], bb[k], acc[rf], 0, 0, 0);
    __builtin_amdgcn_s_setprio(0);

    if (g < 7) {   // WAR-safe single-buffer prefetch of tile g+1
      const short* gBn = gB + (size_t)(g + 1) * 64 * DD;
      #pragma unroll
      for (int k = 0; k < 4; ++k)
        bb[k] = *(const frag_ab*)(gBn + k * 32);
    }
    __builtin_amdgcn_sched_barrier(0);  // pin loads before the epilogue

    // Epilogue: sAcc += exp2(C*sim)  (pre-scaled inputs).
    #pragma unroll
    for (int rf = 0; rf < 4; ++rf)
      #pragma unroll
      for (int r = 0; r < 4; ++r)
        sAcc[rf][r] += __builtin_amdgcn_exp2f(acc[rf][r]);
  }

  // Fold 16 cols (l16 lanes) -> per-row partial per colO group.
  #pragma unroll
  for (int rf = 0; rf < 4; ++rf)
    #pragma unroll
    for (int r = 0; r < 4; ++r) {
      float s = sAcc[rf][r];
      s += __shfl_xor(s, 1, 64);
      s += __shfl_xor(s, 2, 64);
      s += __shfl_xor(s, 4, 64);
      s += __shfl_xor(s, 8, 64);
      if (l16 == 0) sS[rowH * 64 + rf * 16 + quad * 4 + r][colO] = s;
    }
  __syncthreads();
  if (t < 256)
    pS[(size_t)(bx * 256 + t) * CTG + by] =
        (sS[t][0] + sS[t][1]) + (sS[t][2] + sS[t][3]);
  __syncthreads();   // all pS stores issued (vmcnt drained per-wave)

  // -------- Last-arriver finisher for this bx group ----------------------
  if (t == 0) {
    __threadfence();                          // release: L2 writeback (cross-XCD)
    unsigned int old = atomicAdd(&cnt[bx], 1u);
    sLast = (old == 15u);
  }
  __syncthreads();
  if (!sLast) return;
  __threadfence();                            // acquire: invalidate stale caches

  float wloss = 0.f;                          // valid on lane 0
  #pragma unroll 1
  for (int rr = 0; rr < 16; ++rr) {           // 16 rows per wave
    int gr = bx * 256 + wave * 16 + rr;       // 0..4095
    int idx = gr & (NN - 1), half = gr >> 11;
    float S = (lane < CTG) ? pS[(size_t)gr * CTG + lane] : 0.f;
    #pragma unroll
    for (int sh = 1; sh < 16; sh <<= 1) S += __shfl_xor(S, sh, 64);
    // dots vs: self (gr), pos ((1-half)*NN+idx), aug3 (4096+idx), aug4 (6144+idx)
    unsigned int ua = ((const unsigned int*)(Bn + (size_t)gr * DD))[lane];
    unsigned int ub = ((const unsigned int*)(Bn + (size_t)((1 - half) * NN + idx) * DD))[lane];
    unsigned int uc = ((const unsigned int*)(Bn + (size_t)(2 * NN + idx) * DD))[lane];
    unsigned int ud = ((const unsigned int*)(Bn + (size_t)(3 * NN + idx) * DD))[lane];
    float a0 = __uint_as_float((ua & 0xffffu) << 16), a1 = __uint_as_float(ua & 0xffff0000u);
    float b0 = __uint_as_float((ub & 0xffffu) << 16), b1 = __uint_as_float(ub & 0xffff0000u);
    float c0 = __uint_as_float((uc & 0xffffu) << 16), c1 = __uint_as_float(uc & 0xffff0000u);
    float d0 = __uint_as_float((ud & 0xffffu) << 16), d1 = __uint_as_float(ud & 0xffff0000u);
    float daa = a0 * a0 + a1 * a1;       // = C * (self dot)
    float dab = a0 * b0 + a1 * b1;       // = C * (pos dot)
    float dac = a0 * c0 + a1 * c1;
    float dad = a0 * d0 + a1 * d1;
    #pragma unroll
    for (int sh = 1; sh < 64; sh <<= 1) {
      daa += __shfl_xor(daa, sh, 64);
      dab += __shfl_xor(dab, sh, 64);
      dac += __shfl_xor(dac, sh, 64);
      dad += __shfl_xor(dad, sh, 64);
    }
    // subtract masked diagonals: self + aug3 + aug4 (pos block stays)
    float Sc = S - __builtin_amdgcn_exp2f(daa)
                 - __builtin_amdgcn_exp2f(dac)
                 - __builtin_amdgcn_exp2f(dad);
    if (lane == 0) wloss += LN2 * (__log2f(Sc) - dab);
  }
  if (lane == 0) sS[wave][0] = wloss;
  __syncthreads();
  if (t == 0) {
    float acc = 0.f;
    #pragma unroll
    for (int w = 0; w < 16; ++w) acc += sS[w][0];
    atomicAdd(out, acc * (1.0f / (float)TWO_N));
  }
}

extern "C" void kernel_launch(void* const* d_in, const int* in_sizes, int n_in,
                              void* d_out, int out_size, void* d_ws, size_t ws_size,
                              hipStream_t stream) {
  (void)in_sizes; (void)n_in; (void)out_size; (void)ws_size;
  const float* p0 = (const float*)d_in[0];
  const float* p1 = (const float*)d_in[1];
  const float* p2 = (const float*)d_in[2];
  const float* p3 = (const float*)d_in[3];

  // ws layout: Bn bf16 [8192][128] (2 MB) | pS f32 [4096][16] (256 KB) |
  //            cnt u32 [16]
  short* Bn = (short*)d_ws;
  float* pS = (float*)((char*)d_ws + (size_t)FOUR_N * DD * sizeof(short));
  unsigned int* cnt = (unsigned int*)((char*)d_ws +
      (size_t)FOUR_N * DD * sizeof(short) + (size_t)TWO_N * CTG * sizeof(float));
  float* out = (float*)d_out;

  knorm<<<256, 1024, 0, stream>>>(p0, p1, p2, p3, Bn, out, cnt);
  kgemm<<<256, 1024, 0, stream>>>(Bn, pS, cnt, out);
}

// Round 6
// 111.006 us; speedup vs baseline: 1.4921x; 1.1712x over previous
//
#include <hip/hip_runtime.h>
#include <hip/hip_bf16.h>

// NT-Xent with more negatives: N=2048, D=128, k=4 augs.
// sim = norm(z[4096,128]) @ norm(z_all[8192,128])^T * 2   (T=0.5)
// loss = mean_rows( logsumexp(masked sim) - pos )
// R11: LDS-free MFMA GEMM, fragments direct from L2-resident Bn (2 MB).
// R12: tile rebalance (256x512) -> NULL (not L2-BW bound).
// R13: pre-scaled Bn (epilogue = exp2+add), prefetch reorder -> NULL.
// R14: cooperative fusion -> 165us. R15: threadfence last-arriver -> 130us.
//   Joint diagnosis: grid.sync()/__threadfence() emit buffer_wbl2 = full
//   per-XCD L2 writeback; 256 blocks flushing = the 80us stall (kgemm at
//   MfmaUtil 3.9%, HBM 1.2%, FETCH 5.4MB => stalled, not spilled; VGPR=64
//   is arch-VGPR half of a 64v+64a unified-file split, not a spill).
// R16: fence-FREE kfin fusion: pS written with agent-scope relaxed atomics
//   (sc1 write-through, device-visible, NO wbl2). __syncthreads() drains
//   vmcnt (stores acked at coherent point) before lane0's relaxed
//   atomicAdd(cnt[bx]); 16th arriver finishes its 256 rows reading pS via
//   sc1 loads (also dodges stale poison lines in its own XCD L2).
//   2 launches. Pre-commit: delta < 3us => only knorm fusion left, then
//   ROOFLINE.

#define NN      2048
#define DD      128
#define TWO_N   4096
#define FOUR_N  8192
#define CTG     16     // col groups (8192 / 512)
#define SQRT_C  1.6986436f            // sqrt(2*log2(e)); scaled dot = 2*log2e*sim
#define LN2     0.6931471805599453f

using frag_ab = __attribute__((ext_vector_type(8))) short;  // 8 bf16 = 16 B
using f32x4   = __attribute__((ext_vector_type(4))) float;

// ---------------- Kernel 1: L2-normalize rows -> bf16 * SQRT_C -----------
// 256 blocks x 1024 thr, 32 rows/block (half-wave per row, float4/lane).
// Also zeroes out[0] and cnt[0..15].
__global__ __launch_bounds__(1024) void knorm(const float* __restrict__ p0,
                                              const float* __restrict__ p1,
                                              const float* __restrict__ p2,
                                              const float* __restrict__ p3,
                                              short* __restrict__ Bn,
                                              float* __restrict__ out,
                                              unsigned int* __restrict__ cnt) {
  int t = threadIdx.x, wave = t >> 6, lane = t & 63;
  if (blockIdx.x == 0) {
    if (t == 0) out[0] = 0.0f;
    if (t < 16) cnt[t] = 0u;
  }
  int l32 = lane & 31;
  int row = blockIdx.x * 32 + wave * 2 + (lane >> 5);   // 0..8191
  int q = row >> 11, idx = row & (NN - 1);
  const float* src = (q == 0) ? p0 : (q == 1) ? p1 : (q == 2) ? p2 : p3;
  float4 v = ((const float4*)(src + (size_t)idx * DD))[l32];
  float ss = v.x * v.x + v.y * v.y + v.z * v.z + v.w * v.w;
  #pragma unroll
  for (int sh = 1; sh < 32; sh <<= 1) ss += __shfl_xor(ss, sh, 64);
  float inv = SQRT_C / fmaxf(sqrtf(ss), 1e-8f);
  __hip_bfloat162 h0, h1;
  h0.x = __float2bfloat16(v.x * inv); h0.y = __float2bfloat16(v.y * inv);
  h1.x = __float2bfloat16(v.z * inv); h1.y = __float2bfloat16(v.w * inv);
  uint2 u;
  u.x = *(unsigned int*)&h0;
  u.y = *(unsigned int*)&h1;
  *(uint2*)(Bn + (size_t)row * DD + l32 * 4) = u;
}

// ---------------- Kernel 2: LDS-free GEMM + sumexp + fused finisher ------
// 256 blocks x 1024 thr = 16 waves = 4/SIMD, 1 block/CU.
// Block (bx,by): 256 A-rows x 512 B-cols (8 streamed 64-col tiles).
// pS[row][by] = sum_{cols in 512-group} exp2(C*sim)  (= exp(2*sim)),
// written with agent-scope (sc1) atomics -> device-visible, no L2 flush.
// Last arriver of each bx group finishes rows bx*256..+256.
__global__ __launch_bounds__(1024, 4) void kgemm(const short* __restrict__ Bn,
                                                 float* __restrict__ pS,
                                                 unsigned int* __restrict__ cnt,
                                                 float* __restrict__ out) {
  __shared__ float sS[256][5];   // merge scratch; finisher reuses [w][0]
  __shared__ int sLast;

  int t = threadIdx.x, wave = t >> 6, lane = t & 63;
  int quad = lane >> 4, l16 = lane & 15;
  int rowH = wave >> 2, colO = wave & 3;

  // XCD-bijective swizzle: xcd = lin & 7 (dispatch round-robin).
  int lin = blockIdx.x;                      // 0..255
  int by = (lin & 7) | ((lin >> 7) << 3);    // 0..15
  int bx = (lin >> 3) & 15;                  // 0..15

  // Hoist A fragments: rows bx*256 + rowH*64 + rf*16 + l16, chunk k*4+quad.
  const short* gA = Bn + (size_t)(bx * 256 + rowH * 64 + l16) * DD + quad * 8;
  frag_ab a[4][4];                                  // [k][rf]
  #pragma unroll
  for (int rf = 0; rf < 4; ++rf)
    #pragma unroll
    for (int k = 0; k < 4; ++k)
      a[k][rf] = *(const frag_ab*)(gA + (size_t)rf * 16 * DD + k * 32);

  // B base: col (sim-space) = by*512 + g*64 + colO*16 + l16.
  const short* gB = Bn + (size_t)(by * 512 + colO * 16 + l16) * DD + quad * 8;

  float sAcc[4][4];
  #pragma unroll
  for (int rf = 0; rf < 4; ++rf)
    #pragma unroll
    for (int r = 0; r < 4; ++r) sAcc[rf][r] = 0.f;

  // Prime tile 0's B fragments (single buffer, overwritten each iter).
  frag_ab bb[4];
  #pragma unroll
  for (int k = 0; k < 4; ++k)
    bb[k] = *(const frag_ab*)(gB + k * 32);

  #pragma unroll 1
  for (int g = 0; g < 8; ++g) {
    f32x4 acc[4];
    #pragma unroll
    for (int rf = 0; rf < 4; ++rf) acc[rf] = (f32x4){0.f, 0.f, 0.f, 0.f};

    __builtin_amdgcn_s_setprio(1);
    #pragma unroll
    for (int k = 0; k < 4; ++k)
      #pragma unroll
      for (int rf = 0; rf < 4; ++rf)
        acc[rf] = __builtin_amdgcn_mfma_f32_16x16x32_bf16(a[k][rf], bb[k], acc[rf], 0, 0, 0);
    __builtin_amdgcn_s_setprio(0);

    if (g < 7) {   // WAR-safe single-buffer prefetch of tile g+1
      const short* gBn = gB + (size_t)(g + 1) * 64 * DD;
      #pragma unroll
      for (int k = 0; k < 4; ++k)
        bb[k] = *(const frag_ab*)(gBn + k * 32);
    }
    __builtin_amdgcn_sched_barrier(0);  // pin loads before the epilogue

    // Epilogue: sAcc += exp2(C*sim)  (pre-scaled inputs).
    #pragma unroll
    for (int rf = 0; rf < 4; ++rf)
      #pragma unroll
      for (int r = 0; r < 4; ++r)
        sAcc[rf][r] += __builtin_amdgcn_exp2f(acc[rf][r]);
  }

  // Fold 16 cols (l16 lanes) -> per-row partial per colO group.
  #pragma unroll
  for (int rf = 0; rf < 4; ++rf)
    #pragma unroll
    for (int r = 0; r < 4; ++r) {
      float s = sAcc[rf][r];
      s += __shfl_xor(s, 1, 64);
      s += __shfl_xor(s, 2, 64);
      s += __shfl_xor(s, 4, 64);
      s += __shfl_xor(s, 8, 64);
      if (l16 == 0) sS[rowH * 64 + rf * 16 + quad * 4 + r][colO] = s;
    }
  __syncthreads();
  if (t < 256) {
    float v = (sS[t][0] + sS[t][1]) + (sS[t][2] + sS[t][3]);
    // sc1 write-through store: device-visible once vmcnt-acked, no wbl2.
    __hip_atomic_store(&pS[(size_t)(bx * 256 + t) * CTG + by], v,
                       __ATOMIC_RELAXED, __HIP_MEMORY_SCOPE_AGENT);
  }
  // __syncthreads drains every wave's vmcnt (sc1 stores acked at the
  // coherent point) before lane0 announces completion.
  __syncthreads();

  // -------- Last-arriver finisher for this bx group ----------------------
  if (t == 0) {
    unsigned int old = __hip_atomic_fetch_add(&cnt[bx], 1u, __ATOMIC_RELAXED,
                                              __HIP_MEMORY_SCOPE_AGENT);
    sLast = (old == 15u);
  }
  __syncthreads();
  if (!sLast) return;

  float wloss = 0.f;                          // valid on lane 0
  #pragma unroll 1
  for (int rr = 0; rr < 16; ++rr) {           // 16 rows per wave
    int gr = bx * 256 + wave * 16 + rr;       // 0..4095
    int idx = gr & (NN - 1), half = gr >> 11;
    float S = 0.f;
    if (lane < CTG)
      S = __hip_atomic_load(&pS[(size_t)gr * CTG + lane],
                            __ATOMIC_RELAXED, __HIP_MEMORY_SCOPE_AGENT);
    #pragma unroll
    for (int sh = 1; sh < 16; sh <<= 1) S += __shfl_xor(S, sh, 64);
    // dots vs: self (gr), pos ((1-half)*NN+idx), aug3 (4096+idx), aug4 (6144+idx)
    unsigned int ua = ((const unsigned int*)(Bn + (size_t)gr * DD))[lane];
    unsigned int ub = ((const unsigned int*)(Bn + (size_t)((1 - half) * NN + idx) * DD))[lane];
    unsigned int uc = ((const unsigned int*)(Bn + (size_t)(2 * NN + idx) * DD))[lane];
    unsigned int ud = ((const unsigned int*)(Bn + (size_t)(3 * NN + idx) * DD))[lane];
    float a0 = __uint_as_float((ua & 0xffffu) << 16), a1 = __uint_as_float(ua & 0xffff0000u);
    float b0 = __uint_as_float((ub & 0xffffu) << 16), b1 = __uint_as_float(ub & 0xffff0000u);
    float c0 = __uint_as_float((uc & 0xffffu) << 16), c1 = __uint_as_float(uc & 0xffff0000u);
    float d0 = __uint_as_float((ud & 0xffffu) << 16), d1 = __uint_as_float(ud & 0xffff0000u);
    float daa = a0 * a0 + a1 * a1;       // = C * (self dot)
    float dab = a0 * b0 + a1 * b1;       // = C * (pos dot)
    float dac = a0 * c0 + a1 * c1;
    float dad = a0 * d0 + a1 * d1;
    #pragma unroll
    for (int sh = 1; sh < 64; sh <<= 1) {
      daa += __shfl_xor(daa, sh, 64);
      dab += __shfl_xor(dab, sh, 64);
      dac += __shfl_xor(dac, sh, 64);
      dad += __shfl_xor(dad, sh, 64);
    }
    // subtract masked diagonals: self + aug3 + aug4 (pos block stays)
    float Sc = S - __builtin_amdgcn_exp2f(daa)
                 - __builtin_amdgcn_exp2f(dac)
                 - __builtin_amdgcn_exp2f(dad);
    if (lane == 0) wloss += LN2 * (__log2f(Sc) - dab);
  }
  if (lane == 0) sS[wave][0] = wloss;
  __syncthreads();
  if (t == 0) {
    float acc = 0.f;
    #pragma unroll
    for (int w = 0; w < 16; ++w) acc += sS[w][0];
    atomicAdd(out, acc * (1.0f / (float)TWO_N));
  }
}

extern "C" void kernel_launch(void* const* d_in, const int* in_sizes, int n_in,
                              void* d_out, int out_size, void* d_ws, size_t ws_size,
                              hipStream_t stream) {
  (void)in_sizes; (void)n_in; (void)out_size; (void)ws_size;
  const float* p0 = (const float*)d_in[0];
  const float* p1 = (const float*)d_in[1];
  const float* p2 = (const float*)d_in[2];
  const float* p3 = (const float*)d_in[3];

  // ws layout: Bn bf16 [8192][128] (2 MB) | pS f32 [4096][16] (256 KB) |
  //            cnt u32 [16]
  short* Bn = (short*)d_ws;
  float* pS = (float*)((char*)d_ws + (size_t)FOUR_N * DD * sizeof(short));
  unsigned int* cnt = (unsigned int*)((char*)d_ws +
      (size_t)FOUR_N * DD * sizeof(short) + (size_t)TWO_N * CTG * sizeof(float));
  float* out = (float*)d_out;

  knorm<<<256, 1024, 0, stream>>>(p0, p1, p2, p3, Bn, out, cnt);
  kgemm<<<256, 1024, 0, stream>>>(Bn, pS, cnt, out);
}

// Round 7
// 102.866 us; speedup vs baseline: 1.6102x; 1.0791x over previous
//
#include <hip/hip_runtime.h>
#include <hip/hip_bf16.h>

// NT-Xent with more negatives: N=2048, D=128, k=4 augs.
// sim = norm(z[4096,128]) @ norm(z_all[8192,128])^T * 2   (T=0.5)
// loss = mean_rows( logsumexp(masked sim) - pos )
// R11: LDS-free MFMA GEMM, fragments direct from L2-resident Bn (2 MB).
// R12: tile rebalance (256x512) -> NULL (not L2-BW bound).
// R13: pre-scaled Bn (epilogue = exp2+add), prefetch reorder -> NULL.
// R14: cooperative fusion -> 165us (grid.sync = per-XCD L2 wb storm).
// R15: threadfence last-arriver -> 130us (same wbl2 poison).
// R16: sc1 fence-free last-arriver -> 111us: finisher tail collapsed to
//   16 blocks x 16-rows-serial at depressed clock. Fusion is ANTI-optimal
//   here: boundaries cost ~5us, serial tails cost 25us.
// R17: revert to R13 3-kernel structure, keep the two safe widenings:
//   knorm 256x1024 (8x smaller dispatch), kfin 1024 blocks x 1 row/wave
//   (serial chain depth 4x down). kgemm = R13 verbatim.
//   Pre-commit: wall within noise of 96 => DVFS-window roofline.

#define NN      2048
#define DD      128
#define TWO_N   4096
#define FOUR_N  8192
#define CTG     16     // col groups (8192 / 512)
#define SQRT_C  1.6986436f            // sqrt(2*log2(e)); scaled dot = 2*log2e*sim
#define LN2     0.6931471805599453f

using frag_ab = __attribute__((ext_vector_type(8))) short;  // 8 bf16 = 16 B
using f32x4   = __attribute__((ext_vector_type(4))) float;

// ---------------- Kernel 1: L2-normalize rows -> bf16 * SQRT_C -----------
// 256 blocks x 1024 thr, 32 rows/block (half-wave per row, float4/lane).
__global__ __launch_bounds__(1024) void knorm(const float* __restrict__ p0,
                                              const float* __restrict__ p1,
                                              const float* __restrict__ p2,
                                              const float* __restrict__ p3,
                                              short* __restrict__ Bn,
                                              float* __restrict__ out) {
  int t = threadIdx.x, wave = t >> 6, lane = t & 63;
  if (blockIdx.x == 0 && t == 0) out[0] = 0.0f;
  int l32 = lane & 31;
  int row = blockIdx.x * 32 + wave * 2 + (lane >> 5);   // 0..8191
  int q = row >> 11, idx = row & (NN - 1);
  const float* src = (q == 0) ? p0 : (q == 1) ? p1 : (q == 2) ? p2 : p3;
  float4 v = ((const float4*)(src + (size_t)idx * DD))[l32];
  float ss = v.x * v.x + v.y * v.y + v.z * v.z + v.w * v.w;
  #pragma unroll
  for (int sh = 1; sh < 32; sh <<= 1) ss += __shfl_xor(ss, sh, 64);
  float inv = SQRT_C / fmaxf(sqrtf(ss), 1e-8f);
  __hip_bfloat162 h0, h1;
  h0.x = __float2bfloat16(v.x * inv); h0.y = __float2bfloat16(v.y * inv);
  h1.x = __float2bfloat16(v.z * inv); h1.y = __float2bfloat16(v.w * inv);
  uint2 u;
  u.x = *(unsigned int*)&h0;
  u.y = *(unsigned int*)&h1;
  *(uint2*)(Bn + (size_t)row * DD + l32 * 4) = u;
}

// ---------------- Kernel 2: LDS-free GEMM + partial sumexp ----------------
// 256 blocks x 1024 thr = 16 waves = 4/SIMD, 1 block/CU.
// Block: 256 A-rows x 512 B-cols (8 streamed 64-col tiles).
// Wave (rowH=w>>2, colO=w&3): rows rowH*64..+64, cols colO*16..+16 of each
// tile. Fragments straight from global (L2/L1-resident).
// pS[row][by] = sum_{cols in 512-group} exp2(C*sim)   (= exp(2*sim)).
__global__ __launch_bounds__(1024, 4) void kgemm(const short* __restrict__ Bn,
                                                 float* __restrict__ pS) {
  __shared__ float sS[256][5];   // +1 pad

  int t = threadIdx.x, wave = t >> 6, lane = t & 63;
  int quad = lane >> 4, l16 = lane & 15;
  int rowH = wave >> 2, colO = wave & 3;

  // XCD-bijective swizzle: xcd = lin & 7 (dispatch round-robin).
  int lin = blockIdx.x;                      // 0..255
  int by = (lin & 7) | ((lin >> 7) << 3);    // 0..15
  int bx = (lin >> 3) & 15;                  // 0..15

  // Hoist A fragments: rows bx*256 + rowH*64 + rf*16 + l16, chunk k*4+quad.
  const short* gA = Bn + (size_t)(bx * 256 + rowH * 64 + l16) * DD + quad * 8;
  frag_ab a[4][4];                                  // [k][rf]
  #pragma unroll
  for (int rf = 0; rf < 4; ++rf)
    #pragma unroll
    for (int k = 0; k < 4; ++k)
      a[k][rf] = *(const frag_ab*)(gA + (size_t)rf * 16 * DD + k * 32);

  // B base: col (sim-space) = by*512 + g*64 + colO*16 + l16.
  const short* gB = Bn + (size_t)(by * 512 + colO * 16 + l16) * DD + quad * 8;

  float sAcc[4][4];
  #pragma unroll
  for (int rf = 0; rf < 4; ++rf)
    #pragma unroll
    for (int r = 0; r < 4; ++r) sAcc[rf][r] = 0.f;

  // Prime tile 0's B fragments (single buffer, overwritten each iter).
  frag_ab bb[4];
  #pragma unroll
  for (int k = 0; k < 4; ++k)
    bb[k] = *(const frag_ab*)(gB + k * 32);

  #pragma unroll 1
  for (int g = 0; g < 8; ++g) {
    f32x4 acc[4];
    #pragma unroll
    for (int rf = 0; rf < 4; ++rf) acc[rf] = (f32x4){0.f, 0.f, 0.f, 0.f};

    __builtin_amdgcn_s_setprio(1);
    #pragma unroll
    for (int k = 0; k < 4; ++k)
      #pragma unroll
      for (int rf = 0; rf < 4; ++rf)
        acc[rf] = __builtin_amdgcn_mfma_f32_16x16x32_bf16(a[k][rf], bb[k], acc[rf], 0, 0, 0);
    __builtin_amdgcn_s_setprio(0);

    if (g < 7) {   // WAR-safe single-buffer prefetch of tile g+1
      const short* gBn = gB + (size_t)(g + 1) * 64 * DD;
      #pragma unroll
      for (int k = 0; k < 4; ++k)
        bb[k] = *(const frag_ab*)(gBn + k * 32);
    }
    __builtin_amdgcn_sched_barrier(0);  // pin loads before the epilogue

    // Epilogue: sAcc += exp2(C*sim)  (pre-scaled inputs).
    #pragma unroll
    for (int rf = 0; rf < 4; ++rf)
      #pragma unroll
      for (int r = 0; r < 4; ++r)
        sAcc[rf][r] += __builtin_amdgcn_exp2f(acc[rf][r]);
  }

  // Fold 16 cols (l16 lanes) -> per-row partial per colO group.
  #pragma unroll
  for (int rf = 0; rf < 4; ++rf)
    #pragma unroll
    for (int r = 0; r < 4; ++r) {
      float s = sAcc[rf][r];
      s += __shfl_xor(s, 1, 64);
      s += __shfl_xor(s, 2, 64);
      s += __shfl_xor(s, 4, 64);
      s += __shfl_xor(s, 8, 64);
      if (l16 == 0) sS[rowH * 64 + rf * 16 + quad * 4 + r][colO] = s;
    }
  __syncthreads();
  if (t < 256)
    pS[(size_t)(bx * 256 + t) * CTG + by] =
        (sS[t][0] + sS[t][1]) + (sS[t][2] + sS[t][3]);
}

// ---------------- Kernel 3: finisher (1024 blocks x 256 thr) --------------
// Block b handles rows [b*4, b*4+4), ONE row per wave (serial depth 1):
// merge 16 group-partials, subtract 3 masked diagonal exps (self, aug3,
// aug4), add pos term, block-reduce, one atomicAdd into out.
// Pre-scaled domain: loss = ln2 * (log2(Sc) - dab_scaled).
__global__ __launch_bounds__(256) void kfin(const short* __restrict__ Bn,
                                            const float* __restrict__ pS,
                                            float* __restrict__ out) {
  int t = threadIdx.x, wave = t >> 6, lane = t & 63;
  __shared__ float sRed[4];

  int gr = blockIdx.x * 4 + wave;                   // 0..4095
  int idx = gr & (NN - 1), half = gr >> 11;
  float S = (lane < CTG) ? pS[(size_t)gr * CTG + lane] : 0.f;
  #pragma unroll
  for (int sh = 1; sh < 16; sh <<= 1) S += __shfl_xor(S, sh, 64);
  // dots vs: self (gr), pos ((1-half)*NN+idx), aug3 (4096+idx), aug4 (6144+idx)
  unsigned int ua = ((const unsigned int*)(Bn + (size_t)gr * DD))[lane];
  unsigned int ub = ((const unsigned int*)(Bn + (size_t)((1 - half) * NN + idx) * DD))[lane];
  unsigned int uc = ((const unsigned int*)(Bn + (size_t)(2 * NN + idx) * DD))[lane];
  unsigned int ud = ((const unsigned int*)(Bn + (size_t)(3 * NN + idx) * DD))[lane];
  float a0 = __uint_as_float((ua & 0xffffu) << 16), a1 = __uint_as_float(ua & 0xffff0000u);
  float b0 = __uint_as_float((ub & 0xffffu) << 16), b1 = __uint_as_float(ub & 0xffff0000u);
  float c0 = __uint_as_float((uc & 0xffffu) << 16), c1 = __uint_as_float(uc & 0xffff0000u);
  float d0 = __uint_as_float((ud & 0xffffu) << 16), d1 = __uint_as_float(ud & 0xffff0000u);
  float daa = a0 * a0 + a1 * a1;       // = C * (self dot)
  float dab = a0 * b0 + a1 * b1;       // = C * (pos dot)
  float dac = a0 * c0 + a1 * c1;
  float dad = a0 * d0 + a1 * d1;
  #pragma unroll
  for (int sh = 1; sh < 64; sh <<= 1) {
    daa += __shfl_xor(daa, sh, 64);
    dab += __shfl_xor(dab, sh, 64);
    dac += __shfl_xor(dac, sh, 64);
    dad += __shfl_xor(dad, sh, 64);
  }
  // subtract masked diagonals: self + aug3 + aug4 (pos block stays)
  float Sc = S - __builtin_amdgcn_exp2f(daa)
               - __builtin_amdgcn_exp2f(dac)
               - __builtin_amdgcn_exp2f(dad);
  float loss = LN2 * (__log2f(Sc) - dab);
  if (lane == 0) sRed[wave] = loss;
  __syncthreads();
  if (t == 0)
    atomicAdd(out, (sRed[0] + sRed[1] + sRed[2] + sRed[3]) * (1.0f / (float)TWO_N));
}

extern "C" void kernel_launch(void* const* d_in, const int* in_sizes, int n_in,
                              void* d_out, int out_size, void* d_ws, size_t ws_size,
                              hipStream_t stream) {
  (void)in_sizes; (void)n_in; (void)out_size; (void)ws_size;
  const float* p0 = (const float*)d_in[0];
  const float* p1 = (const float*)d_in[1];
  const float* p2 = (const float*)d_in[2];
  const float* p3 = (const float*)d_in[3];

  // ws layout: Bn bf16 [8192][128] (2 MB) | pS f32 [4096][16] (256 KB)
  short* Bn = (short*)d_ws;
  float* pS = (float*)((char*)d_ws + (size_t)FOUR_N * DD * sizeof(short));
  float* out = (float*)d_out;

  knorm<<<256, 1024, 0, stream>>>(p0, p1, p2, p3, Bn, out);
  kgemm<<<256, 1024, 0, stream>>>(Bn, pS);
  kfin<<<TWO_N / 4, 256, 0, stream>>>(Bn, pS, out);
}

// Round 8
// 97.064 us; speedup vs baseline: 1.7065x; 1.0598x over previous
//
#include <hip/hip_runtime.h>
#include <hip/hip_bf16.h>

// NT-Xent with more negatives: N=2048, D=128, k=4 augs.
// sim = norm(z[4096,128]) @ norm(z_all[8192,128])^T * 2   (T=0.5)
// loss = mean_rows( logsumexp(masked sim) - pos )
// R11: LDS-free MFMA GEMM, fragments direct from L2-resident Bn (2 MB).
// R12: tile rebalance (256x512) -> NULL (not L2-BW bound).
// R13: pre-scaled Bn (epilogue = exp2+add), prefetch reorder -> NULL.
//   => 96.2us, best config.
// R14: cooperative fusion -> 165us (grid.sync = per-XCD L2 wb storm).
// R15: threadfence last-arriver -> 130us (same wbl2 poison).
// R16: sc1 fence-free last-arriver -> 111us (16-block serial finisher tail).
// R17: knorm 256x1024 + kfin 1024-block "widenings" -> 102.9us REGRESSION:
//   dispatch shape is exquisitely sensitive; R13's grid shapes are the
//   empirical optimum (kfin 1024 blocks = 4x dispatch tail; 1024-thr knorm
//   blocks = coarser scheduling grain).
// R18: restore R13 VERBATIM (best harness-verified: 96.2us).
//   Pre-commit: ~96 => wall = 42us fill + DVFS window + 3 optimal
//   dispatches, twice proven insensitive to cycle cuts => ROOFLINE.

#define NN      2048
#define DD      128
#define TWO_N   4096
#define FOUR_N  8192
#define CTG     16     // col groups (8192 / 512)
#define SQRT_C  1.6986436f            // sqrt(2*log2(e)); scaled dot = 2*log2e*sim
#define LN2     0.6931471805599453f

using frag_ab = __attribute__((ext_vector_type(8))) short;  // 8 bf16 = 16 B
using f32x4   = __attribute__((ext_vector_type(4))) float;

// ---------------- Kernel 1: L2-normalize rows -> bf16 * SQRT_C -----------
__global__ __launch_bounds__(256) void knorm(const float* __restrict__ p0,
                                             const float* __restrict__ p1,
                                             const float* __restrict__ p2,
                                             const float* __restrict__ p3,
                                             short* __restrict__ Bn,
                                             float* __restrict__ out) {
  if (blockIdx.x == 0 && threadIdx.x == 0) out[0] = 0.0f;
  int wave = threadIdx.x >> 6, lane = threadIdx.x & 63;
  int row = blockIdx.x * 4 + wave;                 // 0..8191
  int q = row >> 11, idx = row & (NN - 1);
  const float* src = (q == 0) ? p0 : (q == 1) ? p1 : (q == 2) ? p2 : p3;
  const float2* s2 = (const float2*)(src + (size_t)idx * DD);
  float2 v = s2[lane];
  float ss = v.x * v.x + v.y * v.y;
  #pragma unroll
  for (int sh = 1; sh < 64; sh <<= 1) ss += __shfl_xor(ss, sh, 64);
  float inv = SQRT_C / fmaxf(sqrtf(ss), 1e-8f);
  __hip_bfloat162 o;
  o.x = __float2bfloat16(v.x * inv);
  o.y = __float2bfloat16(v.y * inv);
  ((__hip_bfloat162*)(Bn + (size_t)row * DD))[lane] = o;
}

// ---------------- Kernel 2: LDS-free GEMM + partial sumexp ----------------
// 256 blocks x 1024 thr = 16 waves = 4/SIMD, 1 block/CU.
// Block: 256 A-rows x 512 B-cols (8 streamed 64-col tiles).
// Wave (rowH=w>>2, colO=w&3): rows rowH*64..+64, cols colO*16..+16 of each
// tile. Fragments straight from global (L2/L1-resident).
// pS[row][by] = sum_{cols in 512-group} exp2(C*sim)   (= exp(2*sim)).
__global__ __launch_bounds__(1024, 4) void kgemm(const short* __restrict__ Bn,
                                                 float* __restrict__ pS) {
  __shared__ float sS[256][5];   // +1 pad

  int t = threadIdx.x, wave = t >> 6, lane = t & 63;
  int quad = lane >> 4, l16 = lane & 15;
  int rowH = wave >> 2, colO = wave & 3;

  // XCD-bijective swizzle: xcd = lin & 7 (dispatch round-robin).
  int lin = blockIdx.x;                      // 0..255
  int by = (lin & 7) | ((lin >> 7) << 3);    // 0..15
  int bx = (lin >> 3) & 15;                  // 0..15

  // Hoist A fragments: rows bx*256 + rowH*64 + rf*16 + l16, chunk k*4+quad.
  const short* gA = Bn + (size_t)(bx * 256 + rowH * 64 + l16) * DD + quad * 8;
  frag_ab a[4][4];                                  // [k][rf], 64 VGPR
  #pragma unroll
  for (int rf = 0; rf < 4; ++rf)
    #pragma unroll
    for (int k = 0; k < 4; ++k)
      a[k][rf] = *(const frag_ab*)(gA + (size_t)rf * 16 * DD + k * 32);

  // B base: col (sim-space) = by*512 + g*64 + colO*16 + l16.
  const short* gB = Bn + (size_t)(by * 512 + colO * 16 + l16) * DD + quad * 8;

  float sAcc[4][4];
  #pragma unroll
  for (int rf = 0; rf < 4; ++rf)
    #pragma unroll
    for (int r = 0; r < 4; ++r) sAcc[rf][r] = 0.f;

  // Prime tile 0's B fragments (single buffer, overwritten each iter).
  frag_ab bb[4];
  #pragma unroll
  for (int k = 0; k < 4; ++k)
    bb[k] = *(const frag_ab*)(gB + k * 32);

  #pragma unroll 1
  for (int g = 0; g < 8; ++g) {
    f32x4 acc[4];
    #pragma unroll
    for (int rf = 0; rf < 4; ++rf) acc[rf] = (f32x4){0.f, 0.f, 0.f, 0.f};

    __builtin_amdgcn_s_setprio(1);
    #pragma unroll
    for (int k = 0; k < 4; ++k)
      #pragma unroll
      for (int rf = 0; rf < 4; ++rf)
        acc[rf] = __builtin_amdgcn_mfma_f32_16x16x32_bf16(a[k][rf], bb[k], acc[rf], 0, 0, 0);
    __builtin_amdgcn_s_setprio(0);

    if (g < 7) {   // WAR-safe single-buffer prefetch of tile g+1
      const short* gBn = gB + (size_t)(g + 1) * 64 * DD;
      #pragma unroll
      for (int k = 0; k < 4; ++k)
        bb[k] = *(const frag_ab*)(gBn + k * 32);
    }
    __builtin_amdgcn_sched_barrier(0);  // pin loads before the epilogue

    // Epilogue: sAcc += exp2(C*sim)  (pre-scaled inputs).
    #pragma unroll
    for (int rf = 0; rf < 4; ++rf)
      #pragma unroll
      for (int r = 0; r < 4; ++r)
        sAcc[rf][r] += __builtin_amdgcn_exp2f(acc[rf][r]);
  }

  // Fold 16 cols (l16 lanes) -> per-row partial per colO group.
  #pragma unroll
  for (int rf = 0; rf < 4; ++rf)
    #pragma unroll
    for (int r = 0; r < 4; ++r) {
      float s = sAcc[rf][r];
      s += __shfl_xor(s, 1, 64);
      s += __shfl_xor(s, 2, 64);
      s += __shfl_xor(s, 4, 64);
      s += __shfl_xor(s, 8, 64);
      if (l16 == 0) sS[rowH * 64 + rf * 16 + quad * 4 + r][colO] = s;
    }
  __syncthreads();
  if (t < 256)
    pS[(size_t)(bx * 256 + t) * CTG + by] =
        (sS[t][0] + sS[t][1]) + (sS[t][2] + sS[t][3]);
}

// ---------------- Kernel 3: finisher (256 blocks x 256 thr) ---------------
// Block b handles rows [b*16, b*16+16): merge 16 group-partials, subtract
// the 3 masked diagonal exps (self, aug3-diag, aug4-diag), add pos term,
// block-reduce, one atomicAdd into out. All dots are pre-scaled (C*s):
// loss = ln2 * (log2(Sc) - dab_scaled).
__global__ __launch_bounds__(256) void kfin(const short* __restrict__ Bn,
                                            const float* __restrict__ pS,
                                            float* __restrict__ out) {
  int t = threadIdx.x, wave = t >> 6, lane = t & 63;
  int grBase = blockIdx.x * 16;
  __shared__ float sRed[4];

  float wloss = 0.f;                                // valid on lane 0
  #pragma unroll 1
  for (int rr = wave; rr < 16; rr += 4) {           // 4 rows per wave
    int gr = grBase + rr;
    int idx = gr & (NN - 1), half = gr >> 11;
    float S = (lane < CTG) ? pS[(size_t)gr * CTG + lane] : 0.f;
    #pragma unroll
    for (int sh = 1; sh < 16; sh <<= 1) S += __shfl_xor(S, sh, 64);
    // dots vs: self (gr), pos ((1-half)*NN+idx), aug3 (4096+idx), aug4 (6144+idx)
    unsigned int ua = ((const unsigned int*)(Bn + (size_t)gr * DD))[lane];
    unsigned int ub = ((const unsigned int*)(Bn + (size_t)((1 - half) * NN + idx) * DD))[lane];
    unsigned int uc = ((const unsigned int*)(Bn + (size_t)(2 * NN + idx) * DD))[lane];
    unsigned int ud = ((const unsigned int*)(Bn + (size_t)(3 * NN + idx) * DD))[lane];
    float a0 = __uint_as_float((ua & 0xffffu) << 16), a1 = __uint_as_float(ua & 0xffff0000u);
    float b0 = __uint_as_float((ub & 0xffffu) << 16), b1 = __uint_as_float(ub & 0xffff0000u);
    float c0 = __uint_as_float((uc & 0xffffu) << 16), c1 = __uint_as_float(uc & 0xffff0000u);
    float d0 = __uint_as_float((ud & 0xffffu) << 16), d1 = __uint_as_float(ud & 0xffff0000u);
    float daa = a0 * a0 + a1 * a1;       // = C * (self dot)
    float dab = a0 * b0 + a1 * b1;       // = C * (pos dot)
    float dac = a0 * c0 + a1 * c1;
    float dad = a0 * d0 + a1 * d1;
    #pragma unroll
    for (int sh = 1; sh < 64; sh <<= 1) {
      daa += __shfl_xor(daa, sh, 64);
      dab += __shfl_xor(dab, sh, 64);
      dac += __shfl_xor(dac, sh, 64);
      dad += __shfl_xor(dad, sh, 64);
    }
    // subtract masked diagonals: self + aug3 + aug4 (pos block stays)
    float Sc = S - __builtin_amdgcn_exp2f(daa)
                 - __builtin_amdgcn_exp2f(dac)
                 - __builtin_amdgcn_exp2f(dad);
    float loss = LN2 * (__log2f(Sc) - dab);
    if (lane == 0) wloss += loss;
  }
  if (lane == 0) sRed[wave] = wloss;
  __syncthreads();
  if (t == 0)
    atomicAdd(out, (sRed[0] + sRed[1] + sRed[2] + sRed[3]) * (1.0f / (float)TWO_N));
}

extern "C" void kernel_launch(void* const* d_in, const int* in_sizes, int n_in,
                              void* d_out, int out_size, void* d_ws, size_t ws_size,
                              hipStream_t stream) {
  (void)in_sizes; (void)n_in; (void)out_size; (void)ws_size;
  const float* p0 = (const float*)d_in[0];
  const float* p1 = (const float*)d_in[1];
  const float* p2 = (const float*)d_in[2];
  const float* p3 = (const float*)d_in[3];

  // ws layout: Bn bf16 [8192][128] (2 MB) | pS f32 [4096][16] (256 KB)
  short* Bn = (short*)d_ws;
  float* pS = (float*)((char*)d_ws + (size_t)FOUR_N * DD * sizeof(short));
  float* out = (float*)d_out;

  knorm<<<FOUR_N / 4, 256, 0, stream>>>(p0, p1, p2, p3, Bn, out);
  kgemm<<<256, 1024, 0, stream>>>(Bn, pS);
  kfin<<<TWO_N / 16, 256, 0, stream>>>(Bn, pS, out);
}